// Round 3
// baseline (222.555 us; speedup 1.0000x reference)
//
#include <hip/hip_runtime.h>
#include <math.h>

constexpr int N_ROWS = 1024;
constexpr int DDIM   = 512;
constexpr int C_CLS  = 100000;
constexpr float MARG = 0.4f;
constexpr int WPAD   = 100352;              // 392*256
constexpr int NT2    = 392;                 // class tiles (BN=256)
constexpr int NT_FB  = 782;                 // fallback class tiles (BN=128)

typedef __attribute__((ext_vector_type(8))) short bf16x8;   // 8 bf16 (4 VGPRs)
typedef __attribute__((ext_vector_type(4))) float f32x4;
typedef __attribute__((address_space(1))) const void gvoid_t;
typedef __attribute__((address_space(3))) void lvoid_t;

__device__ __forceinline__ unsigned int f2bf(float x) {
    union { float f; unsigned int u; } v; v.f = x;
    return (v.u + 0x7FFFu + ((v.u >> 16) & 1u)) >> 16;   // RNE to bf16 bits
}

__device__ __forceinline__ float wave_sum(float s) {
    #pragma unroll
    for (int m = 1; m < 64; m <<= 1) s += __shfl_xor(s, m, 64);
    return s;
}

// ---- per-row norm of embs -> g[i], normalized bf16 ehat ----
__global__ __launch_bounds__(256) void prep_embs(const float* __restrict__ embs,
                                                 float* __restrict__ g,
                                                 unsigned short* __restrict__ ehat) {
    const int row  = blockIdx.x * 4 + (threadIdx.x >> 6);
    const int lane = threadIdx.x & 63;
    const float4* src = (const float4*)(embs + (size_t)row * DDIM + lane * 8);
    const float4 a = src[0], b = src[1];
    float ss = a.x*a.x + a.y*a.y + a.z*a.z + a.w*a.w
             + b.x*b.x + b.y*b.y + b.z*b.z + b.w*b.w;
    ss = wave_sum(ss);
    const float norm = sqrtf(ss);
    const float rn = 1.f / norm;
    if (lane == 0) {
        float gg = (norm - 20.f) / sqrtf(10000.f + 1e-3f) * 0.333f;
        gg = fminf(fmaxf(gg, -1.f), 1.f);
        g[row] = gg;
    }
    uint4 pk;
    pk.x = f2bf(a.x*rn) | (f2bf(a.y*rn) << 16);
    pk.y = f2bf(a.z*rn) | (f2bf(a.w*rn) << 16);
    pk.z = f2bf(b.x*rn) | (f2bf(b.y*rn) << 16);
    pk.w = f2bf(b.z*rn) | (f2bf(b.w*rn) << 16);
    *(uint4*)(ehat + (size_t)row * DDIM + lane * 8) = pk;
}

// ---- normalized bf16 weight ----
__global__ __launch_bounds__(256) void prep_what(const float* __restrict__ w,
                                                 unsigned short* __restrict__ what) {
    const int row  = blockIdx.x * 4 + (threadIdx.x >> 6);
    const int lane = threadIdx.x & 63;
    const float4* src = (const float4*)(w + (size_t)row * DDIM + lane * 8);
    const float4 a = src[0], b = src[1];
    float ss = a.x*a.x + a.y*a.y + a.z*a.z + a.w*a.w
             + b.x*b.x + b.y*b.y + b.z*b.z + b.w*b.w;
    ss = wave_sum(ss);
    const float rn = rsqrtf(ss);
    uint4 pk;
    pk.x = f2bf(a.x*rn) | (f2bf(a.y*rn) << 16);
    pk.y = f2bf(a.z*rn) | (f2bf(a.w*rn) << 16);
    pk.z = f2bf(b.x*rn) | (f2bf(b.y*rn) << 16);
    pk.w = f2bf(b.z*rn) | (f2bf(b.w*rn) << 16);
    *(uint4*)(what + (size_t)row * DDIM + lane * 8) = pk;
}

// ---- fallback helper: 1/||weight[c]|| ----
__global__ __launch_bounds__(256) void prep_wnorm(const float* __restrict__ w,
                                                  float* __restrict__ rnormw) {
    const int row  = blockIdx.x * 4 + (threadIdx.x >> 6);
    const int lane = threadIdx.x & 63;
    const float4* src = (const float4*)(w + (size_t)row * DDIM + lane * 8);
    const float4 a = src[0], b = src[1];
    float ss = a.x*a.x + a.y*a.y + a.z*a.z + a.w*a.w
             + b.x*b.x + b.y*b.y + b.z*b.z + b.w*b.w;
    ss = wave_sum(ss);
    if (lane == 0) rnormw[row] = 1.f / sqrtf(ss);
}

// ==== swizzle helpers (st-style XOR at 16B granularity within a 128B row) ====
// stage: linear LDS dest (gload_lds), inverse-swizzled global source.
__device__ __forceinline__ void stage_slab(const unsigned short* __restrict__ src,
                                           int grow0, const unsigned short* lds_row0,
                                           int kbase, int lane) {
    const int lr  = lane >> 3;                 // row within this wave's 8-row slab
    const int c16 = (lane & 7) ^ lr;           // logical 16B chunk for physical slot lane&7
    const unsigned short* g = src + (size_t)(grow0 + lr) * DDIM + kbase + c16 * 8;
    __builtin_amdgcn_global_load_lds((gvoid_t*)g, (lvoid_t*)lds_row0, 16, 0, 0);
}
// fragment read: swizzled address. row ≡ lane&15 (mod 16) so row&7 == lane&7.
__device__ __forceinline__ bf16x8 frag_ld(const unsigned short* tile, int row, int ks, int lane) {
    const int c16 = ((ks << 2) + (lane >> 4)) ^ (lane & 7);
    return *(const bf16x8*)(tile + row * 64 + c16 * 8);
}

// ==== 256x256 / BK=64, double-buffered, 4-sub-phase schedule ====
__global__ __launch_bounds__(512, 2) void gemm256(
        const unsigned short* __restrict__ ehat,   // [1024][512] bf16
        const unsigned short* __restrict__ what,   // [WPAD][512] bf16
        const int* __restrict__ labels,
        float* __restrict__ psum,                  // [1024][NT2]
        float* __restrict__ dlab)
{
    __shared__ __align__(16) unsigned short As[2][256 * 64];  // 64 KB
    __shared__ __align__(16) unsigned short Bs[2][256 * 64];  // 64 KB

    const int tid  = threadIdx.x;
    const int lane = tid & 63;
    const int wv   = tid >> 6;
    const int wr   = wv >> 2;     // 0..1  (128 rows each)
    const int wc   = wv & 3;      // 0..3  (64 cols each)

    // T1: bijective XCD swizzle; grid = 1568 = 8*196. Consecutive wgid share tile_c.
    const int nchunk = (int)gridDim.x >> 3;
    const int wgid   = ((int)blockIdx.x & 7) * nchunk + ((int)blockIdx.x >> 3);
    const int tile_c = wgid >> 2;
    const int tile_r = wgid & 3;
    const int row0   = tile_r * 256;
    const int col0   = tile_c * 256;

    f32x4 acc[8][4];
    #pragma unroll
    for (int m = 0; m < 8; ++m)
        #pragma unroll
        for (int n = 0; n < 4; ++n) acc[m][n] = f32x4{0.f, 0.f, 0.f, 0.f};

    // prologue: stage K-tile 0 into buf 0 (8 block-wide issues)
    #pragma unroll
    for (int s = 0; s < 8; ++s) {
        const int base = (s & 3) * 64 + wv * 8;
        if (s < 4) stage_slab(ehat, row0 + base, &As[0][base * 64], 0, lane);
        else       stage_slab(what, col0 + base, &Bs[0][base * 64], 0, lane);
    }
    asm volatile("s_waitcnt vmcnt(0)" ::: "memory");
    __builtin_amdgcn_s_barrier();

    for (int h = 0; h < 8; ++h) {                    // 8 K-tiles of 64
        const int cur = h & 1;
        const unsigned short* At = As[cur];
        const unsigned short* Bt = Bs[cur];
        const unsigned short* An = As[cur ^ 1];
        const unsigned short* Bn = Bs[cur ^ 1];
        const int kn = (h + 1) * 64;
        const bool do_stage = (h < 7);

        bf16x8 af[4][2], bf[4][2];

        #pragma unroll
        for (int q = 0; q < 4; ++q) {                // (mh,nh) = (q>>1, q&1)
            const int mh = q >> 1, nh = q & 1;
            // ---- ds_read register subtile ----
            if (q == 0 || q == 2) {
                #pragma unroll
                for (int m = 0; m < 4; ++m)
                    #pragma unroll
                    for (int ks = 0; ks < 2; ++ks)
                        af[m][ks] = frag_ld(At, wr * 128 + (mh * 4 + m) * 16 + (lane & 15), ks, lane);
            }
            if (q == 0 || q == 1) {
                #pragma unroll
                for (int n = 0; n < 2; ++n)
                    #pragma unroll
                    for (int ks = 0; ks < 2; ++ks)
                        bf[nh * 2 + n][ks] = frag_ld(Bt, wc * 64 + (nh * 2 + n) * 16 + (lane & 15), ks, lane);
            }
            // ---- stage next K-tile (3,3,2,0 issues across phases) ----
            if (do_stage) {
                #pragma unroll
                for (int s = 0; s < 8; ++s) {
                    const bool mine = (q == 0) ? (s < 3) : (q == 1) ? (s >= 3 && s < 6)
                                    : (q == 2) ? (s >= 6) : false;
                    if (mine) {
                        const int base = (s & 3) * 64 + wv * 8;
                        if (s < 4) stage_slab(ehat, row0 + base, &An[base * 64], kn, lane);
                        else       stage_slab(what, col0 + base, &Bn[base * 64], kn, lane);
                    }
                }
            }
            __builtin_amdgcn_s_barrier();
            asm volatile("s_waitcnt lgkmcnt(0)" ::: "memory");
            __builtin_amdgcn_s_setprio(1);
            #pragma unroll
            for (int m = 0; m < 4; ++m)
                #pragma unroll
                for (int n = 0; n < 2; ++n)
                    #pragma unroll
                    for (int ks = 0; ks < 2; ++ks)
                        acc[mh * 4 + m][nh * 2 + n] =
                            __builtin_amdgcn_mfma_f32_16x16x32_bf16(af[m][ks], bf[nh * 2 + n][ks],
                                                                    acc[mh * 4 + m][nh * 2 + n], 0, 0, 0);
            __builtin_amdgcn_s_setprio(0);
            if (q == 3) asm volatile("s_waitcnt vmcnt(0)" ::: "memory");  // once per K-tile
            __builtin_amdgcn_s_barrier();
        }
    }

    // ---- epilogue: clip, label capture, exp-sum; LDS reused as reduction buffer ----
    float* red = (float*)&As[0][0];                  // 4*256 floats
    #pragma unroll
    for (int m = 0; m < 8; ++m) {
        #pragma unroll
        for (int j = 0; j < 4; ++j) {
            const int lrow  = wr * 128 + m * 16 + ((lane >> 4) << 2) + j;
            const int r_abs = row0 + lrow;
            const int lab   = labels[r_abs];
            float s = 0.f;
            #pragma unroll
            for (int n = 0; n < 4; ++n) {
                const int c_abs = col0 + wc * 64 + n * 16 + (lane & 15);
                float v = acc[m][n][j];
                v = fminf(fmaxf(v, -0.999f), 0.999f);
                if (c_abs == lab) dlab[r_abs] = v;
                if (c_abs < C_CLS) s += __expf(64.f * v - 64.f);
            }
            #pragma unroll
            for (int msk = 1; msk < 16; msk <<= 1) s += __shfl_xor(s, msk, 64);
            if ((lane & 15) == 0) red[wc * 256 + lrow] = s;
        }
    }
    __syncthreads();
    for (int t = tid; t < 256; t += 512)
        psum[(size_t)(row0 + t) * NT2 + tile_c] = red[t] + red[256 + t] + red[512 + t] + red[768 + t];
}

// ==== fallback 128^2 GEMM (round-1 verified path, fp32 weight) ====
__global__ __launch_bounds__(256, 2) void gemm_fused_fb(
        const unsigned short* __restrict__ ehat,
        const float* __restrict__ weight,
        const float* __restrict__ rnormw,
        const int* __restrict__ labels,
        float* __restrict__ psum,
        float* __restrict__ dlab)
{
    constexpr int BM = 128, BN = 128, BK = 32;
    __shared__ __align__(16) unsigned short Asf[BM * BK];
    __shared__ __align__(16) unsigned short Bsf[BN * BK];
    __shared__ float redbuf[2][BM];

    const int bid    = blockIdx.x;
    const int tile_c = bid >> 3;
    const int tile_r = bid & 7;
    const int row0   = tile_r * BM;
    const int col0   = tile_c * BN;

    const int tid  = threadIdx.x;
    const int lane = tid & 63;
    const int wv   = tid >> 6;
    const int wr   = wv >> 1;
    const int wc   = wv & 1;

    f32x4 acc[4][4];
    #pragma unroll
    for (int m = 0; m < 4; ++m)
        #pragma unroll
        for (int n = 0; n < 4; ++n) acc[m][n] = f32x4{0.f, 0.f, 0.f, 0.f};

    const int kq    = tid & 7;
    const int brow0 = tid >> 3;
    int   cidx[4];
    float rnv[4];
    #pragma unroll
    for (int p = 0; p < 4; ++p) {
        int c = col0 + p * 32 + brow0;
        c = c < C_CLS ? c : C_CLS - 1;
        cidx[p] = c;
        rnv[p]  = rnormw[c];
    }

    for (int kt = 0; kt < DDIM / BK; ++kt) {
        const int kbase = kt * BK;
        #pragma unroll
        for (int call = 0; call < 2; ++call) {
            const int chunk = call * 256 + tid;
            const uint4 d = *(const uint4*)(ehat + (size_t)(row0 + (chunk >> 2)) * DDIM
                                            + kbase + (chunk & 3) * 8);
            *(uint4*)(Asf + chunk * 8) = d;
        }
        #pragma unroll
        for (int p = 0; p < 4; ++p) {
            const float4 wd = *(const float4*)(weight + (size_t)cidx[p] * DDIM + kbase + kq * 4);
            const float r = rnv[p];
            const unsigned int lo = f2bf(wd.x * r) | (f2bf(wd.y * r) << 16);
            const unsigned int hi = f2bf(wd.z * r) | (f2bf(wd.w * r) << 16);
            *(uint2*)(Bsf + (p * 32 + brow0) * BK + kq * 4) = make_uint2(lo, hi);
        }
        __syncthreads();
        bf16x8 af[4], bfr[4];
        const int lr  = lane & 15;
        const int lko = (lane >> 4) * 8;
        #pragma unroll
        for (int m = 0; m < 4; ++m)
            af[m] = *(const bf16x8*)(Asf + (wr * 64 + m * 16 + lr) * BK + lko);
        #pragma unroll
        for (int n = 0; n < 4; ++n)
            bfr[n] = *(const bf16x8*)(Bsf + (wc * 64 + n * 16 + lr) * BK + lko);
        #pragma unroll
        for (int m = 0; m < 4; ++m)
            #pragma unroll
            for (int n = 0; n < 4; ++n)
                acc[m][n] = __builtin_amdgcn_mfma_f32_16x16x32_bf16(af[m], bfr[n], acc[m][n], 0, 0, 0);
        __syncthreads();
    }

    #pragma unroll
    for (int m = 0; m < 4; ++m) {
        #pragma unroll
        for (int j = 0; j < 4; ++j) {
            const int lrow  = wr * 64 + m * 16 + ((lane >> 4) << 2) + j;
            const int r_abs = row0 + lrow;
            const int lab   = labels[r_abs];
            float s = 0.f;
            #pragma unroll
            for (int n = 0; n < 4; ++n) {
                const int c_abs = col0 + wc * 64 + n * 16 + (lane & 15);
                float v = acc[m][n][j];
                v = fminf(fmaxf(v, -0.999f), 0.999f);
                if (c_abs == lab) dlab[r_abs] = v;
                if (c_abs < C_CLS) s += __expf(64.f * v - 64.f);
            }
            #pragma unroll
            for (int msk = 1; msk < 16; msk <<= 1) s += __shfl_xor(s, msk, 64);
            if ((lane & 15) == 0) redbuf[wc][lrow] = s;
        }
    }
    __syncthreads();
    for (int t = tid; t < BM; t += 256)
        psum[(size_t)(row0 + t) * NT_FB + tile_c] = redbuf[0][t] + redbuf[1][t];
}

// ---- per-row combine + margin correction at label ----
__global__ __launch_bounds__(256) void reduce_rows(const float* __restrict__ psum,
                                                   const float* __restrict__ dlab,
                                                   const float* __restrict__ g,
                                                   float* __restrict__ losses, int nt) {
    const int row  = blockIdx.x * 4 + (threadIdx.x >> 6);
    const int lane = threadIdx.x & 63;
    const float* p = psum + (size_t)row * nt;
    float s = 0.f;
    for (int t = lane; t < nt; t += 64) s += p[t];
    s = wave_sum(s);
    if (lane == 0) {
        const float v  = dlab[row];
        const float gg = g[row];
        float th = acosf(v) - MARG * gg;
        th = fminf(fmaxf(th, 0.f), 3.14159265358979323846f);
        const float vm = cosf(th) - (1.f + MARG) * gg;
        s = s - __expf(64.f * v - 64.f) + __expf(64.f * vm - 64.f);
        losses[row] = 64.f + logf(s) - 64.f * vm;
    }
}

__global__ __launch_bounds__(256) void final_mean(const float* __restrict__ losses,
                                                  float* __restrict__ out) {
    const int tid = threadIdx.x;
    float s = 0.f;
    #pragma unroll
    for (int i = 0; i < 4; ++i) s += losses[tid + i * 256];
    s = wave_sum(s);
    __shared__ float red[4];
    if ((tid & 63) == 0) red[tid >> 6] = s;
    __syncthreads();
    if (tid == 0) out[0] = (red[0] + red[1] + red[2] + red[3]) * (1.f / 1024.f);
}

extern "C" void kernel_launch(void* const* d_in, const int* in_sizes, int n_in,
                              void* d_out, int out_size, void* d_ws, size_t ws_size,
                              hipStream_t stream) {
    const float* embs   = (const float*)d_in[0];
    const float* weight = (const float*)d_in[1];
    const int*   labels = (const int*)d_in[2];
    float* out = (float*)d_out;
    float* ws  = (float*)d_ws;

    const size_t WHAT_F = (size_t)WPAD * DDIM / 2;
    const size_t EHAT_F = (size_t)N_ROWS * DDIM / 2;
    const size_t PSUM_F = (size_t)N_ROWS * NT2;
    const size_t NEED_F = WHAT_F + EHAT_F + PSUM_F + 3 * 1024;

    if (ws_size >= NEED_F * sizeof(float)) {
        unsigned short* what = (unsigned short*)ws;
        unsigned short* ehat = (unsigned short*)(ws + WHAT_F);
        float* psum   = ws + WHAT_F + EHAT_F;
        float* gbuf   = psum + PSUM_F;
        float* dlab   = gbuf + 1024;
        float* losses = dlab + 1024;

        prep_embs<<<N_ROWS / 4, 256, 0, stream>>>(embs, gbuf, ehat);
        prep_what<<<C_CLS / 4, 256, 0, stream>>>(weight, what);
        gemm256<<<NT2 * 4, 512, 0, stream>>>(ehat, what, labels, psum, dlab);
        reduce_rows<<<N_ROWS / 4, 256, 0, stream>>>(psum, dlab, gbuf, losses, NT2);
        final_mean<<<1, 256, 0, stream>>>(losses, out);
    } else {
        float* rnormw = ws + 0;
        float* gbuf   = ws + 100352;
        float* dlab   = ws + 101376;
        float* losses = ws + 102400;
        unsigned short* ehat = (unsigned short*)(ws + 103424);
        float* psum   = ws + 103424 + 262144;

        prep_embs <<<N_ROWS / 4, 256, 0, stream>>>(embs, gbuf, ehat);
        prep_wnorm<<<C_CLS / 4, 256, 0, stream>>>(weight, rnormw);
        gemm_fused_fb<<<NT_FB * 8, 256, 0, stream>>>(ehat, weight, rnormw, labels, psum, dlab);
        reduce_rows<<<N_ROWS / 4, 256, 0, stream>>>(psum, dlab, gbuf, losses, NT_FB);
        final_mean<<<1, 256, 0, stream>>>(losses, out);
    }
}